// Round 1
// 241.987 us; speedup vs baseline: 1.0034x; 1.0034x over previous
//
#include <hip/hip_runtime.h>

// SplitEmbedding: out[t, :] = (input_ids[t] in tune_ids) ? train_weight[row(t), :]
//                                                        : base_weight[input_ids[t], :]
// tune_ids is SORTED (1024 entries); "later duplicates win" == upper_bound - 1.
//
// v2 changes vs previous best (242.8 us, kernel-only ~56 us inferred):
//  - tune_ids staged into LDS once per 512-thread block (was: every wave did a
//    64-distinct-cache-line VMEM gather for round-1 segment heads).
//    Segment heads live in a separate lds_heads[64] array -> round 1 reads
//    heads[lane] (bank = lane%32, 2-way aliasing = free); round 2 reads 16
//    consecutive words with 4x same-address broadcast (conflict-free).
//  - Speculative base-row loads issued BEFORE the search so the row-gather
//    latency overlaps staging + search; only the rare (~2%, wave-uniform)
//    tune hits reload from train_weight.
//  - 2 tokens per wave: 6 float4 payload loads in flight per wave.
// Output stores stay nontemporal: 100 MB streaming write must not evict the
// gathered base_weight rows from L2/L3.

#define EMBED_DIM 768
#define WAVES_PER_BLOCK 8
#define BLOCK_THREADS (WAVES_PER_BLOCK * 64)       // 512
#define TOKENS_PER_WAVE 2
#define TOKENS_PER_BLOCK (WAVES_PER_BLOCK * TOKENS_PER_WAVE)  // 16
#define NUM_TUNE_C 1024

typedef __attribute__((ext_vector_type(4))) float f4;
typedef __attribute__((ext_vector_type(4))) int   i4;

__global__ __launch_bounds__(BLOCK_THREADS) void split_embedding_kernel(
    const int* __restrict__ input_ids,       // [num_tokens]
    const int* __restrict__ tune_ids,        // [num_tune], sorted ascending
    const float* __restrict__ base_weight,   // [VOCAB, EMBED_DIM]
    const float* __restrict__ train_weight,  // [num_tune, EMBED_DIM]
    float* __restrict__ out,                 // [num_tokens, EMBED_DIM]
    int num_tokens, int num_tune)
{
    __shared__ int lds_tune[NUM_TUNE_C];   // full sorted table
    __shared__ int lds_heads[64];          // tune_ids[s*16] for s = 0..63

    const int wave = threadIdx.x >> 6;
    const int lane = threadIdx.x & 63;
    const int tokenA = blockIdx.x * TOKENS_PER_BLOCK + wave * TOKENS_PER_WAVE;
    const int tokenB = tokenA + 1;

    const bool vA = (tokenA < num_tokens);
    const bool vB = (tokenB < num_tokens);

    const int tokA = vA ? input_ids[tokenA] : 0;   // broadcast loads
    const int tokB = vB ? input_ids[tokenB] : 0;

    // ---- Speculative base-row loads: issued before the search so the
    // row-gather latency overlaps the LDS staging + search. Always safe:
    // tok < VOCAB regardless of whether it is a tune token. ----
    const f4* __restrict__ srcA = (const f4*)(base_weight + (size_t)tokA * EMBED_DIM);
    const f4* __restrict__ srcB = (const f4*)(base_weight + (size_t)tokB * EMBED_DIM);
    f4 a0, a1, a2, b0, b1, b2;
    if (vA) { a0 = srcA[lane]; a1 = srcA[lane + 64]; a2 = srcA[lane + 128]; }
    if (vB) { b0 = srcB[lane]; b1 = srcB[lane + 64]; b2 = srcB[lane + 128]; }

    int candA = -1, cvalA = -1;   // upper_bound(tok) - 1 and its value
    int candB = -1, cvalB = -1;

    if (num_tune == NUM_TUNE_C) {
        // ---- stage table into LDS (4 KB, aligned int4 writes) ----
        if (threadIdx.x < NUM_TUNE_C / 4) {
            const i4 v = ((const i4*)tune_ids)[threadIdx.x];
            *(i4*)&lds_tune[threadIdx.x * 4] = v;
            if ((threadIdx.x & 3) == 0) lds_heads[threadIdx.x >> 2] = v.x;
        }
        __syncthreads();

        {   // ---- wave-parallel 2-round search for tokA (64 x 16) ----
            const int v1 = lds_heads[lane];
            const unsigned long long b1 = __ballot(v1 <= tokA);
            const int seg = __popcll(b1) - 1;
            if (seg >= 0) {
                const int v2 = lds_tune[(seg << 4) + (lane & 15)];
                const unsigned long long b2 = __ballot(v2 <= tokA) & 0xFFFFull;
                const int cnt = __popcll(b2);           // >= 1 (head qualifies)
                candA = (seg << 4) + cnt - 1;
                cvalA = __shfl(v2, candA & 15);
            }
        }
        {   // ---- search for tokB ----
            const int v1 = lds_heads[lane];
            const unsigned long long b1 = __ballot(v1 <= tokB);
            const int seg = __popcll(b1) - 1;
            if (seg >= 0) {
                const int v2 = lds_tune[(seg << 4) + (lane & 15)];
                const unsigned long long b2 = __ballot(v2 <= tokB) & 0xFFFFull;
                const int cnt = __popcll(b2);
                candB = (seg << 4) + cnt - 1;
                cvalB = __shfl(v2, candB & 15);
            }
        }
    } else {
        // Generic fallback: serial binary search (wave-uniform).
        if (vA) {
            int lo = 0, hi = num_tune;
            while (lo < hi) {
                const int mid = (lo + hi) >> 1;
                if (tune_ids[mid] <= tokA) lo = mid + 1;
                else                       hi = mid;
            }
            candA = lo - 1;
            if (candA >= 0) cvalA = tune_ids[candA];
        }
        if (vB) {
            int lo = 0, hi = num_tune;
            while (lo < hi) {
                const int mid = (lo + hi) >> 1;
                if (tune_ids[mid] <= tokB) lo = mid + 1;
                else                       hi = mid;
            }
            candB = lo - 1;
            if (candB >= 0) cvalB = tune_ids[candB];
        }
    }

    // ---- rare fixup: tune hit -> replace with train row (wave-uniform) ----
    if (vA && candA >= 0 && cvalA == tokA) {
        const f4* t = (const f4*)(train_weight + (size_t)candA * EMBED_DIM);
        a0 = t[lane]; a1 = t[lane + 64]; a2 = t[lane + 128];
    }
    if (vB && candB >= 0 && cvalB == tokB) {
        const f4* t = (const f4*)(train_weight + (size_t)candB * EMBED_DIM);
        b0 = t[lane]; b1 = t[lane + 64]; b2 = t[lane + 128];
    }

    // ---- coalesced nontemporal stores: 192 float4/row, 3 per lane ----
    f4* dstA = (f4*)(out + (size_t)tokenA * EMBED_DIM);
    f4* dstB = (f4*)(out + (size_t)tokenB * EMBED_DIM);
    if (vA) {
        __builtin_nontemporal_store(a0, dstA + lane);
        __builtin_nontemporal_store(a1, dstA + lane + 64);
        __builtin_nontemporal_store(a2, dstA + lane + 128);
    }
    if (vB) {
        __builtin_nontemporal_store(b0, dstB + lane);
        __builtin_nontemporal_store(b1, dstB + lane + 64);
        __builtin_nontemporal_store(b2, dstB + lane + 128);
    }
}

extern "C" void kernel_launch(void* const* d_in, const int* in_sizes, int n_in,
                              void* d_out, int out_size, void* d_ws, size_t ws_size,
                              hipStream_t stream) {
    const int*   input_ids    = (const int*)d_in[0];
    const int*   tune_ids     = (const int*)d_in[1];
    const float* base_weight  = (const float*)d_in[2];
    const float* train_weight = (const float*)d_in[3];
    float*       out          = (float*)d_out;

    const int num_tokens = in_sizes[0];   // 8 * 4096 = 32768
    const int num_tune   = in_sizes[1];   // 1024

    const int grid = (num_tokens + TOKENS_PER_BLOCK - 1) / TOKENS_PER_BLOCK;
    split_embedding_kernel<<<grid, BLOCK_THREADS, 0, stream>>>(
        input_ids, tune_ids, base_weight, train_weight, out, num_tokens, num_tune);
}